// Round 3
// baseline (71.006 us; speedup 1.0000x reference)
//
#include <hip/hip_runtime.h>
#include <stdint.h>

#define EPS_C 0.0009f   // 0.03^2

typedef __attribute__((address_space(3))) uint8_t* as3_ptr;
typedef const __attribute__((address_space(1))) uint8_t* as1_ptr;

__device__ __forceinline__ float metric_val(float dot, float f, float g) {
    float c    = dot / (f * g);
    float dn   = sqrtf(fmaxf(2.0f - 2.0f * c, 0.0f));
    float dist = (2.0f - dn) * 0.5f;
    float lum  = (2.0f * f * g + EPS_C) / (f * f + g * g + EPS_C);
    float met  = dist * sqrtf(lum);
    return (1.0f - met) * 2.0f;
}

// Grid: 512 blocks x 256 threads (2 blocks/CU -> 2 waves/SIMD for latency hiding).
//   bg = blockIdx >> 6  (8 groups of 8 batch rows; wave w owns b = bg*8 + 2w, +1)
//   mg = blockIdx & 63  (64 groups of 4 modes; same-mg blocks are XCD-affine)
// Each wave keeps its 2 input rows in registers (2 x 16 float4). Mode rows are
// staged global->LDS once per block via global_load_lds (16B width, async, no
// RF round-trip), double-buffered; all 4 waves consume via ds_read_b128.
// Partial mins -> ws[mg*64 + b] (all 4096 slots written every call, so the
// 0xAA ws-poison never survives); simk_reduce folds 64 partials per row.
__global__ __launch_bounds__(256, 2)
void simk_main(const float* __restrict__ inputs, const float* __restrict__ modes,
               float* __restrict__ ws) {
    __shared__ float4 sbuf[2][1024];   // 2 x 16 KB mode-row buffers

    const int tid  = threadIdx.x;
    const int lane = tid & 63;
    const int w    = tid >> 6;
    const int bg   = blockIdx.x >> 6;
    const int mg   = blockIdx.x & 63;
    const int b0   = bg * 8 + w * 2;
    const int b1   = b0 + 1;

    const float4* inp4 = (const float4*)inputs;
    const float4* mod4 = (const float4*)modes;

    // Input rows in registers: float4 index = j*64 + lane (coalesced 1KB/step)
    float4 in0[16], in1[16];
#pragma unroll
    for (int j = 0; j < 16; ++j) in0[j] = inp4[(size_t)b0 * 1024 + j * 64 + lane];
#pragma unroll
    for (int j = 0; j < 16; ++j) in1[j] = inp4[(size_t)b1 * 1024 + j * 64 + lane];

    // Stage mode (mg*4 + 0) into buffer 0: each wave DMAs its quarter (4 KB).
    // LDS dest is wave-uniform base; HW scatters lane i to base + i*16.
    {
        const float4* gm = mod4 + (size_t)(mg * 4) * 1024 + w * 256 + lane;
#pragma unroll
        for (int c = 0; c < 4; ++c) {
            __builtin_amdgcn_global_load_lds((as1_ptr)(gm + c * 64),
                                             (as3_ptr)&sbuf[0][w * 256 + c * 64],
                                             16, 0, 0);
        }
    }

    // Input Frobenius norms (overlaps with the DMA above)
    float s0 = 0.f, s1 = 0.f;
#pragma unroll
    for (int j = 0; j < 16; ++j) {
        s0 += in0[j].x * in0[j].x + in0[j].y * in0[j].y + in0[j].z * in0[j].z + in0[j].w * in0[j].w;
        s1 += in1[j].x * in1[j].x + in1[j].y * in1[j].y + in1[j].z * in1[j].z + in1[j].w * in1[j].w;
    }
#pragma unroll
    for (int sh = 1; sh < 64; sh <<= 1) {
        s0 += __shfl_xor(s0, sh, 64);
        s1 += __shfl_xor(s1, sh, 64);
    }
    const float f0 = sqrtf(s0);
    const float f1 = sqrtf(s1);

    __syncthreads();   // buffer 0 ready (barrier drains vmcnt)

    float min0 = 3.0e38f, min1 = 3.0e38f;

    for (int mi = 0; mi < 4; ++mi) {
        // Prefetch next mode into the other buffer while consuming this one.
        if (mi + 1 < 4) {
            const float4* gm = mod4 + (size_t)(mg * 4 + mi + 1) * 1024 + w * 256 + lane;
            float4* dst = &sbuf[(mi + 1) & 1][w * 256];
#pragma unroll
            for (int c = 0; c < 4; ++c) {
                __builtin_amdgcn_global_load_lds((as1_ptr)(gm + c * 64),
                                                 (as3_ptr)(dst + c * 64),
                                                 16, 0, 0);
            }
        }

        const float4* mp = sbuf[mi & 1];
        // 12 independent FMA chains for ILP
        float d0x = 0.f, d0y = 0.f, d0z = 0.f, d0w = 0.f;
        float d1x = 0.f, d1y = 0.f, d1z = 0.f, d1w = 0.f;
        float qx  = 0.f, qy  = 0.f, qz  = 0.f, qw  = 0.f;
#pragma unroll
        for (int j = 0; j < 16; ++j) {
            float4 v = mp[j * 64 + lane];   // ds_read_b128, conflict-free
            d0x += v.x * in0[j].x; d0y += v.y * in0[j].y;
            d0z += v.z * in0[j].z; d0w += v.w * in0[j].w;
            d1x += v.x * in1[j].x; d1y += v.y * in1[j].y;
            d1z += v.z * in1[j].z; d1w += v.w * in1[j].w;
            qx  += v.x * v.x;      qy  += v.y * v.y;
            qz  += v.z * v.z;      qw  += v.w * v.w;
        }
        float d0 = (d0x + d0y) + (d0z + d0w);
        float d1 = (d1x + d1y) + (d1z + d1w);
        float q  = (qx + qy) + (qz + qw);
#pragma unroll
        for (int sh = 1; sh < 64; sh <<= 1) {
            d0 += __shfl_xor(d0, sh, 64);
            d1 += __shfl_xor(d1, sh, 64);
            q  += __shfl_xor(q,  sh, 64);
        }
        const float g = sqrtf(q);
        min0 = fminf(min0, metric_val(d0, f0, g));
        min1 = fminf(min1, metric_val(d1, f1, g));

        __syncthreads();   // consumption of buf[mi&1] done; prefetch drained
    }

    // Deterministic partial write: each (b, mg) slot written by exactly one wave.
    if (lane == 0) {
        ws[mg * 64 + b0] = min0;
        ws[mg * 64 + b1] = min1;
    }
}

// One wave: thread b folds the 64 mode-group partials for batch row b.
__global__ void simk_reduce(const float* __restrict__ ws, float* __restrict__ out) {
    const int b = threadIdx.x;
    float m = 3.0e38f;
#pragma unroll
    for (int mg = 0; mg < 64; ++mg) m = fminf(m, ws[mg * 64 + b]);
    out[b] = m;
}

extern "C" void kernel_launch(void* const* d_in, const int* in_sizes, int n_in,
                              void* d_out, int out_size, void* d_ws, size_t ws_size,
                              hipStream_t stream) {
    const float* inputs = (const float*)d_in[0];
    const float* modes  = (const float*)d_in[1];
    float* ws  = (float*)d_ws;
    float* out = (float*)d_out;

    simk_main<<<512, 256, 0, stream>>>(inputs, modes, ws);
    simk_reduce<<<1, 64, 0, stream>>>(ws, out);
}